// Round 1
// baseline (163.389 us; speedup 1.0000x reference)
//
#include <hip/hip_runtime.h>
#include <math.h>

// Problem constants (fixed by reference setup_inputs): pred [32,1,512,512] f32
#define IMG_W 512
#define IMG_H 512
#define HW (IMG_W * IMG_H)      // 262144 = 2^18
#define LOGHW 18
#define NIMG 32
#define NTOT (NIMG * HW)        // 8388608
#define TILE 64
#define TPI 64                  // 8x8 tiles of 64x64 per image
#define NTILE (NIMG * TPI)      // 2048
#define EDGE_N (NTILE * 64)     // 131072 entries per edge direction
#define NPAIR (NIMG * 112)      // 56 vertical + 56 horizontal tile-pairs/img
#define RTSTRIDE 2048           // max roots per 64x64 tile (checkerboard bound)
// NOTE (R6/R15 lesson): NO cross-block handshakes inside large grids. R6:
// 2048-way single counter = 56us serialization. R15: per-image 64-way acq_rel
// inside the 2048-block stats grid = 60us of L2 wbl2/inv thrash. Separate tiny
// launches (~4us) always win. 32-way in a 32-block grid (k_tail) is the only
// safe pattern.
// NOTE (R12 lesson): no big register prefetch in k_local — VGPR 16->44
// halved occupancy (66->37%) and cost +11us. Occupancy > manual prefetch.
// NOTE (R8..R14): four structurally different k_local CCLs all land
// 120-121us total; k_local latency floor ~42-46us; harness fixed cost ~55us
// in-window (256MiB ws poison fill = 44us at HBM ceiling — untouchable).
// NOTE (R16, this round): global roots are a subset of local roots (unites
// only demote). k_local exports compact per-tile root lists (~130/tile) +
// per-tile minFg; k_stats (full 33.5MB L re-read) is DELETED — k_tail probes
// only the ~8K candidates/image. 4 launches -> 3.

// ---------------- lock-free min-index union-find ----------------------------
__device__ __forceinline__ void uf_unite(int* L, int a, int b) {
    while (true) {
        int p = ((volatile int*)L)[a];
        while (p != a) { a = p; p = ((volatile int*)L)[a]; }
        p = ((volatile int*)L)[b];
        while (p != b) { b = p; p = ((volatile int*)L)[b]; }
        if (a == b) return;
        if (a < b) { int t = a; a = b; b = t; }  // a > b
        int old = atomicMin(&L[a], b);
        if (old == a) return;
        a = old;
    }
}

// ---------------- K1: CCL + base BCE + edge export + root-list export -------
// One block (512 thr, 8 waves) per 64x64 tile; row width == wave width.
// Pass 1: row-run labels via ballot + fused base BCE + per-thread minFg.
// Pass 2: vertical unites only at contact-run starts (~750/tile).
// Pass 3a: only run-starts chase to root (full compress).
// Pass 3b: every px root = lab[lab[px]] via one ds_read_b128 + gather; write
//   global L (int4); append local roots compactly to this tile's rootList
//   region (LDS-counter reservation, no global atomics, no init needed).
__global__ __launch_bounds__(512) void k_local(const float* __restrict__ pred,
                                               int* __restrict__ L,
                                               float* __restrict__ partials,
                                               int* __restrict__ edges,
                                               int* __restrict__ rootCnt,
                                               int* __restrict__ rootList,
                                               unsigned int* __restrict__ minFgT,
                                               unsigned int* __restrict__ counter) {
    __shared__ int lab[TILE * TILE];   // 16 KB
    __shared__ float swf[8];
    __shared__ unsigned swu[8];
    __shared__ int rootc;
    int tile = blockIdx.x;
    int img = tile >> 6;
    int t = tile & (TPI - 1);
    int ty = t >> 3, tx = t & 7;
    int baseLocal = (ty * TILE) * IMG_W + tx * TILE;  // image-local origin
    const float* pi = pred + ((size_t)img << LOGHW);
    int* Li = L + ((size_t)img << LOGHW);
    int tid = threadIdx.x;
    int lane = tid & 63, wave = tid >> 6;             // wave 0..7
    if (tid == 0) rootc = 0;

    float acc = 0.0f;
    unsigned umn = 0xFFFFFFFFu;
    // ---- pass 1: row-run labels via ballot (wave w handles rows r%8==w) ----
#pragma unroll
    for (int j = 0; j < 8; j++) {
        int row = wave + j * 8;
        int fl = baseLocal + row * IMG_W + lane;      // image-local flat idx
        float p = pi[fl];
        acc += fmaxf(__logf(1.0f - p), -100.0f);      // 1-p exact for p>=0.5
        bool fg = (p >= 0.5f);
        if (fg && fl != 0) umn = min(umn, (unsigned)fl);  // minFg excludes 0
        unsigned long long bal = __ballot(fg);
        unsigned long long starts = bal & ~(bal << 1);
        unsigned long long maskle =
            (lane == 63) ? ~0ULL : ((1ULL << (lane + 1)) - 1ULL);
        int lb = -1;
        if (fg) {
            unsigned long long pre = starts & maskle;  // nonzero when fg
            lb = row * TILE + (63 - __builtin_clzll(pre));
        }
        lab[row * TILE + lane] = lb;
    }
    __syncthreads();
    // ---- pass 2: vertical unites, one per contact-run ----------------------
#pragma unroll
    for (int j = 0; j < 8; j++) {
        int row = wave + j * 8;
        if (row == 0) continue;                   // wave-uniform
        int i = row * TILE + lane;
        bool c = (lab[i] >= 0) && (lab[i - TILE] >= 0);
        unsigned long long cb = __ballot(c);
        unsigned long long cs = cb & ~(cb << 1);  // first lane of each contact
        if ((cs >> lane) & 1ULL) uf_unite(lab, i, i - TILE);
    }
    __syncthreads();
    // ---- pass 3a: run-starts chase to root (path halving + full compress) --
#pragma unroll
    for (int j = 0; j < 8; j++) {
        int row = wave + j * 8;
        int i = row * TILE + lane;
        bool fg = (lab[i] >= 0);
        unsigned long long bal = __ballot(fg);
        unsigned long long st = bal & ~(bal << 1);
        if ((st >> lane) & 1ULL) {
            int x = i, p = lab[x];
            while (p != x) {
                int g = lab[p];
                lab[x] = g;          // halving: benign race, ancestors only
                x = g;
                p = lab[x];
            }
            lab[i] = x;              // full compress for the start entry
        }
    }
    __syncthreads();
    // ---- pass 3b: b128 gather + global write (int4) + root export ----------
    int* rl = rootList + (size_t)tile * RTSTRIDE;
#pragma unroll
    for (int j = 0; j < 2; j++) {
        int i4 = (tid + j * 512) * 4;
        int4 s4 = *(const int4*)&lab[i4];        // one ds_read_b128
        const int* sp = (const int*)&s4;
        int4 o;
        int* op = (int*)&o;
        int rc = 0;
#pragma unroll
        for (int k = 0; k < 4; k++) {
            int s = sp[k];
            if (s < 0) op[k] = -1;
            else {
                int r = lab[s];                  // root (starts compressed)
                op[k] = baseLocal + (r >> 6) * IMG_W + (r & 63);
                if (s == i4 + k) rc++;           // this px IS a local root
            }
        }
        *(int4*)(Li + baseLocal + (i4 >> 6) * IMG_W + (i4 & 63)) = o;
        if (rc) {                                // ~3% of threads
            int base = atomicAdd(&rootc, rc);    // LDS atomic, ~130/tile total
#pragma unroll
            for (int k = 0; k < 4; k++)
                if (sp[k] == i4 + k) rl[base++] = op[k];  // image-local root idx
        }
    }
    // ---- edge export: 4 x 64 labels, coalesced -----------------------------
    if (tid < 256) {
        int e = tid >> 6;                        // 0=T,1=B,2=L,3=R
        int q = tid & 63;
        int px = (e == 0) ? q
               : (e == 1) ? (63 * TILE + q)
               : (e == 2) ? (q * TILE)
               :            (q * TILE + 63);
        int s = lab[px];
        int val = -1;
        if (s >= 0) {
            int r = lab[s];
            val = baseLocal + (r >> 6) * IMG_W + (r & 63);
        }
        edges[e * EDGE_N + tile * 64 + q] = val;
    }
    // ---- base BCE + minFg: wave shuffle reduce (1 barrier, was 9) ----------
#pragma unroll
    for (int o = 32; o > 0; o >>= 1) {
        acc += __shfl_down(acc, o);
        umn = min(umn, (unsigned)__shfl_down((int)umn, o));
    }
    if (lane == 0) { swf[wave] = acc; swu[wave] = umn; }
    __syncthreads();                             // also orders rootc atomics
    if (tid == 0) {
        float s = 0.0f; unsigned m = 0xFFFFFFFFu;
#pragma unroll
        for (int w = 0; w < 8; w++) { s += swf[w]; m = min(m, swu[w]); }
        partials[blockIdx.x] = s;
        rootCnt[tile] = rootc;
        minFgT[tile] = m;
        if (blockIdx.x == 0) *counter = 0u;      // ws is 0xAA-poisoned
    }
}

// ---------------- K2: cross-tile border unites from compact edges -----------
__global__ __launch_bounds__(256) void k_border(const int* __restrict__ edges,
                                                int* __restrict__ L) {
    int gid = blockIdx.x * blockDim.x + threadIdx.x;
    int pair = gid >> 6;                 // wave-uniform
    int lane = gid & 63;
    int a, b, img;
    if (pair < NIMG * 56) {              // vertical: (ty,tx)-(ty,tx+1)
        img = pair / 56;
        int w = pair - img * 56;
        int ty = w / 7, tx = w - ty * 7;
        int tl = img * TPI + ty * 8 + tx;
        a = edges[3 * EDGE_N + tl * 64 + lane];        // right edge of left
        b = edges[2 * EDGE_N + (tl + 1) * 64 + lane];  // left edge of right
    } else {                             // horizontal: (ty,tx)-(ty+1,tx)
        int p2 = pair - NIMG * 56;
        img = p2 / 56;
        int w = p2 - img * 56;
        int ty = w >> 3, tx = w & 7;
        int tu = img * TPI + ty * 8 + tx;
        a = edges[1 * EDGE_N + tu * 64 + lane];        // bottom edge of upper
        b = edges[0 * EDGE_N + (tu + 8) * 64 + lane];  // top edge of lower
    }
    bool c = (a >= 0) && (b >= 0);
    unsigned long long cb = __ballot(c);
    unsigned long long cs = cb & ~(cb << 1);           // contact-run starts
    if ((cs >> lane) & 1ULL)
        uf_unite(L + ((size_t)img << LOGHW), a, b);
}

// ---------------- K3: fused stats (candidate probe) + rv + reduce -----------
// One block per image. Global roots after k_border = {r in local-root list :
// L[r]==r} (unites only demote roots, never create). Probe ~8K candidates
// instead of re-reading 33.5MB of L. v = last_root if >=1; else minFg / 1.
// rv >= 0 (rare: v<=num) falls back to in-block full-L selection + correction
// scan. Last of the 32 blocks (32-way counter in a 32-block grid — the only
// safe handshake pattern) reduces k_local's 2048 base partials + 32 corrs.
__global__ __launch_bounds__(256) void k_tail(const int* __restrict__ rootCnt,
                                              const int* __restrict__ rootList,
                                              const unsigned int* __restrict__ minFgT,
                                              const int* __restrict__ L,
                                              const float* __restrict__ pred,
                                              const float* __restrict__ partials,
                                              float* __restrict__ corr,
                                              unsigned int* __restrict__ counter,
                                              float* __restrict__ out) {
    __shared__ int pre[65];              // inclusive prefix of 64 tile counts
    __shared__ int sc[256], sm[256], sn[256];
    __shared__ int result;
    __shared__ float sf[256];
    __shared__ double sd[256];
    __shared__ unsigned int oldc;
    int img = blockIdx.x, t = threadIdx.x;
    const int* Li = L + ((size_t)img << LOGHW);

    // ---- tile-count prefix (wave 0, shuffle scan) --------------------------
    if (t < 64) {
        int v = rootCnt[img * TPI + t];
#pragma unroll
        for (int o = 1; o < 64; o <<= 1) {
            int u = __shfl_up(v, o);
            if (t >= o) v += u;
        }
        pre[t + 1] = v;
        if (t == 0) pre[0] = 0;
    }
    if (t == 0) result = -2;
    __syncthreads();
    int C = pre[64];                     // total candidates this image (~8K)

    // ---- candidate probe: count survivors + max survivor, 8-wide batched ---
    int cnt = 0, mx = -1;
    for (int k0 = t; k0 < C; k0 += 2048) {
        int rr0 = -1, rr1 = -1, rr2 = -1, rr3 = -1,
            rr4 = -1, rr5 = -1, rr6 = -1, rr7 = -1;
#define PROBE(J, RR)                                                        \
        {                                                                   \
            int k = k0 + (J) * 256;                                         \
            if (k < C) {                                                    \
                int lo = 0, hi = 64;                                        \
                for (int s = 0; s < 6; s++) {                               \
                    int mid = (lo + hi) >> 1;                               \
                    if (pre[mid] <= k) lo = mid; else hi = mid;             \
                }                                                           \
                RR = rootList[(size_t)(img * TPI + lo) * RTSTRIDE           \
                              + (k - pre[lo])];                             \
            }                                                               \
        }
        PROBE(0, rr0) PROBE(1, rr1) PROBE(2, rr2) PROBE(3, rr3)
        PROBE(4, rr4) PROBE(5, rr5) PROBE(6, rr6) PROBE(7, rr7)
#undef PROBE
#define TEST(RR) if ((RR) >= 0 && Li[RR] == (RR)) { cnt++; mx = max(mx, RR); }
        TEST(rr0) TEST(rr1) TEST(rr2) TEST(rr3)
        TEST(rr4) TEST(rr5) TEST(rr6) TEST(rr7)
#undef TEST
    }
    unsigned mnu = (t < 64) ? minFgT[img * TPI + t] : 0xFFFFFFFFu;
    sc[t] = cnt; sm[t] = mx;
    sn[t] = (int)min(mnu, (unsigned)HW);
    __syncthreads();
    for (int s = 128; s > 0; s >>= 1) {
        if (t < s) {
            sc[t] += sc[t + s];
            sm[t] = max(sm[t], sm[t + s]);
            sn[t] = min(sn[t], sn[t + s]);
        }
        __syncthreads();
    }
    int num = sc[0], last_root = sm[0], minFg = sn[0];
    int v;
    if (last_root >= 1) v = last_root;
    else if (last_root == 0) v = (minFg < HW) ? minFg : 1;
    else v = 1;

    // ---- rare path: select v-th surviving root in raster order -------------
    if (v >= 1 && v <= num) {            // block-uniform branch
        int base = t * (HW / 256);       // contiguous 1024-px raster range
        int c = 0;
        for (int j = 0; j < 256; j++) {
            int off = base + j * 4;
            int4 l4 = *(const int4*)(Li + off);
            c += (l4.x == off) + (l4.y == off + 1)
               + (l4.z == off + 2) + (l4.w == off + 3);
        }
        sc[t] = c;
        __syncthreads();
        for (int off = 1; off < 256; off <<= 1) {
            int v2 = (t >= off) ? sc[t - off] : 0;
            __syncthreads();
            sc[t] += v2;
            __syncthreads();
        }
        int inc = sc[t], exc = inc - c;
        if (exc < v && v <= inc) {       // my range holds the v-th root
            int need = v - exc, run = 0;
            for (int j = 0; j < 256; j++) {
                int off = base + j * 4;
                int4 l4 = *(const int4*)(Li + off);
                if (l4.x == off)     { run++; if (run == need) result = off; }
                if (l4.y == off + 1) { run++; if (run == need) result = off + 1; }
                if (l4.z == off + 2) { run++; if (run == need) result = off + 2; }
                if (l4.w == off + 3) { run++; if (run == need) result = off + 3; }
                if (run >= need) break;
            }
        }
        __syncthreads();
    }
    int rvv = result;
    float blocksum = 0.0f;
    if (rvv >= 0) {                      // rare path: scan whole image
        const float* pi = pred + ((size_t)img << LOGHW);
        float acc = 0.0f;
        for (int it = 0; it < HW / 1024; it++) {
            int off = it * 1024 + t * 4;
            float4 p4 = *(const float4*)(pi + off);
            int4 l4 = *(const int4*)(Li + off);
            const float* pp = (const float*)&p4;
            const int* lp = (const int*)&l4;
#pragma unroll
            for (int k = 0; k < 4; k++) {
                int p = lp[k];
                if (p < 0) continue;
                int x = p, q = Li[x];
                while (q != x) { x = q; q = Li[x]; }
                if (x == rvv) {
                    float pr = pp[k];
                    acc += fmaxf(__logf(pr), -100.0f)
                         - fmaxf(__logf(1.0f - pr), -100.0f);
                }
            }
        }
        sf[t] = acc;
        __syncthreads();
        for (int s = 128; s > 0; s >>= 1) {
            if (t < s) sf[t] += sf[t + s];
            __syncthreads();
        }
        blocksum = sf[0];
    }
    if (t == 0) {
        __hip_atomic_store(&corr[img], blocksum, __ATOMIC_RELAXED,
                           __HIP_MEMORY_SCOPE_AGENT);
        oldc = __hip_atomic_fetch_add(counter, 1u, __ATOMIC_ACQ_REL,
                                      __HIP_MEMORY_SCOPE_AGENT);
    }
    __syncthreads();
    if (oldc != NIMG - 1) return;
    // ---- last of 32 blocks: final reduce -----------------------------------
    double acc = 0.0;
#pragma unroll
    for (int j = 0; j < 8; j++) acc += (double)partials[t + j * 256];
    if (t < NIMG)
        acc += (double)__hip_atomic_load(&corr[t], __ATOMIC_ACQUIRE,
                                         __HIP_MEMORY_SCOPE_AGENT);
    sd[t] = acc;
    __syncthreads();
    for (int s = 128; s > 0; s >>= 1) {
        if (t < s) sd[t] += sd[t + s];
        __syncthreads();
    }
    if (t == 0) out[0] = (float)(-sd[0] / (double)NTOT);
}

extern "C" void kernel_launch(void* const* d_in, const int* in_sizes, int n_in,
                              void* d_out, int out_size, void* d_ws, size_t ws_size,
                              hipStream_t stream) {
    const float* pred = (const float*)d_in[0];
    float* out = (float*)d_out;

    char* ws = (char*)d_ws;
    int* L = (int*)ws;                                        // 33.5 MB
    int* edges = (int*)(ws + (size_t)NTOT * 4);               // 2 MB (4 dirs)
    int* rootList = edges + 4 * EDGE_N;                       // 16.8 MB
    int* rootCnt = rootList + (size_t)NTILE * RTSTRIDE;       // 8 KB
    unsigned int* minFgT = (unsigned int*)(rootCnt + NTILE);  // 8 KB
    float* partials = (float*)(minFgT + NTILE);               // 8 KB
    float* corr = partials + NTILE;                           // 128 B
    unsigned int* counter = (unsigned int*)(corr + NIMG);     // 4 B

    k_local<<<dim3(NTILE), dim3(512), 0, stream>>>(pred, L, partials, edges,
                                                   rootCnt, rootList, minFgT,
                                                   counter);
    k_border<<<dim3(NPAIR * 64 / 256), dim3(256), 0, stream>>>(edges, L);
    k_tail<<<dim3(NIMG), dim3(256), 0, stream>>>(rootCnt, rootList, minFgT, L,
                                                 pred, partials, corr, counter,
                                                 out);
}

// Round 2
// 137.892 us; speedup vs baseline: 1.1849x; 1.1849x over previous
//
#include <hip/hip_runtime.h>
#include <math.h>

// Problem constants (fixed by reference setup_inputs): pred [32,1,512,512] f32
#define IMG_W 512
#define IMG_H 512
#define HW (IMG_W * IMG_H)      // 262144 = 2^18
#define LOGHW 18
#define NIMG 32
#define NTOT (NIMG * HW)        // 8388608
#define TILE 64
#define TPI 64                  // 8x8 tiles of 64x64 per image
#define NTILE (NIMG * TPI)      // 2048
#define EDGE_N (NTILE * 64)     // 131072 entries per edge direction
#define NPAIR (NIMG * 112)      // 56 vertical + 56 horizontal tile-pairs/img
#define RTSTRIDE 2048           // max roots per 64x64 tile (checkerboard bound)
// NOTE (R6/R15 lesson): NO cross-block handshakes inside large grids. R6:
// 2048-way single counter = 56us serialization. R15: per-image 64-way acq_rel
// inside the 2048-block stats grid = 60us of L2 wbl2/inv thrash. Separate tiny
// launches (~4us) always win. 32-way in a 32-block grid (k_tail) is the only
// safe pattern.
// NOTE (R12 lesson): no big register prefetch in k_local — VGPR 16->44
// halved occupancy (66->37%) and cost +11us. Occupancy > manual prefetch.
// NOTE (R8..R14): four structurally different k_local CCLs all land
// 120-121us total; k_local latency floor ~42-46us; harness fixed cost ~55us
// in-window (256MiB ws poison fill = 44us at HBM ceiling — untouchable).
// NOTE (R16 lesson): exporting RUN STARTS (s==i) instead of ROOTS (lab[s]==s)
// made the candidate list 4x too big WITH duplicates -> k_tail 51us of
// dependent-latency probes at 1.2% occupancy. Also: per-pixel VALU additions
// to k_local's hot passes (minFg, root test in 3b) cost +6us — k_local is
// VALU/latency bound; only touch sparse diverged paths.
// R17: export from pass 3a chase threads (x==i <=> root, ~270/tile, sparse);
// minFg computed lazily in k_tail's never-taken rare branch; k_tail 512 thr.

// ---------------- lock-free min-index union-find ----------------------------
__device__ __forceinline__ void uf_unite(int* L, int a, int b) {
    while (true) {
        int p = ((volatile int*)L)[a];
        while (p != a) { a = p; p = ((volatile int*)L)[a]; }
        p = ((volatile int*)L)[b];
        while (p != b) { b = p; p = ((volatile int*)L)[b]; }
        if (a == b) return;
        if (a < b) { int t = a; a = b; b = t; }  // a > b
        int old = atomicMin(&L[a], b);
        if (old == a) return;
        a = old;
    }
}

// ---------------- K1: CCL + base BCE + edge export + root-list export -------
// One block (512 thr, 8 waves) per 64x64 tile; row width == wave width.
// Pass 1: row-run labels via ballot + fused base BCE sum.
// Pass 2: vertical unites only at contact-run starts (~750/tile).
// Pass 3a: run-starts chase to root; roots (x==i, ~270/tile) append their
//   image-local index to this tile's rootList segment (LDS counter, sparse).
// Pass 3b: every px root = lab[lab[px]] (b128 read + gather); write global L.
__global__ __launch_bounds__(512) void k_local(const float* __restrict__ pred,
                                               int* __restrict__ L,
                                               float* __restrict__ partials,
                                               int* __restrict__ edges,
                                               int* __restrict__ rootCnt,
                                               int* __restrict__ rootList,
                                               unsigned int* __restrict__ counter) {
    __shared__ int lab[TILE * TILE];   // 16 KB
    __shared__ float swf[8];
    __shared__ int rootc;
    int tile = blockIdx.x;
    int img = tile >> 6;
    int t = tile & (TPI - 1);
    int ty = t >> 3, tx = t & 7;
    int baseLocal = (ty * TILE) * IMG_W + tx * TILE;  // image-local origin
    const float* pi = pred + ((size_t)img << LOGHW);
    int* Li = L + ((size_t)img << LOGHW);
    int tid = threadIdx.x;
    int lane = tid & 63, wave = tid >> 6;             // wave 0..7
    if (tid == 0) rootc = 0;

    float acc = 0.0f;
    // ---- pass 1: row-run labels via ballot (wave w handles rows r%8==w) ----
#pragma unroll
    for (int j = 0; j < 8; j++) {
        int row = wave + j * 8;
        float p = pi[baseLocal + row * IMG_W + lane];
        acc += fmaxf(__logf(1.0f - p), -100.0f);   // 1-p exact for p>=0.5
        bool fg = (p >= 0.5f);
        unsigned long long bal = __ballot(fg);
        unsigned long long starts = bal & ~(bal << 1);
        unsigned long long maskle =
            (lane == 63) ? ~0ULL : ((1ULL << (lane + 1)) - 1ULL);
        int lb = -1;
        if (fg) {
            unsigned long long pre = starts & maskle;   // nonzero when fg
            lb = row * TILE + (63 - __builtin_clzll(pre));
        }
        lab[row * TILE + lane] = lb;
    }
    __syncthreads();
    // ---- pass 2: vertical unites, one per contact-run ----------------------
#pragma unroll
    for (int j = 0; j < 8; j++) {
        int row = wave + j * 8;
        if (row == 0) continue;                   // wave-uniform
        int i = row * TILE + lane;
        bool c = (lab[i] >= 0) && (lab[i - TILE] >= 0);
        unsigned long long cb = __ballot(c);
        unsigned long long cs = cb & ~(cb << 1);  // first lane of each contact
        if ((cs >> lane) & 1ULL) uf_unite(lab, i, i - TILE);
    }
    __syncthreads();
    // ---- pass 3a: run-starts chase to root + sparse root export ------------
    int* rl = rootList + (size_t)tile * RTSTRIDE;
#pragma unroll
    for (int j = 0; j < 8; j++) {
        int row = wave + j * 8;
        int i = row * TILE + lane;
        bool fg = (lab[i] >= 0);
        unsigned long long bal = __ballot(fg);
        unsigned long long st = bal & ~(bal << 1);
        if ((st >> lane) & 1ULL) {
            int x = i, p = lab[x];
            while (p != x) {
                int g = lab[p];
                lab[x] = g;          // halving: benign race, ancestors only
                x = g;
                p = lab[x];
            }
            lab[i] = x;              // full compress for the start entry
            if (x == i) {            // i is a LOCAL ROOT (~270/tile)
                int b = atomicAdd(&rootc, 1);
                rl[b] = baseLocal + (i >> 6) * IMG_W + (i & 63);
            }
        }
    }
    __syncthreads();
    // ---- pass 3b: b128 gather + global write (int4) ------------------------
#pragma unroll
    for (int j = 0; j < 2; j++) {
        int i4 = (tid + j * 512) * 4;
        int4 s4 = *(const int4*)&lab[i4];        // one ds_read_b128
        const int* sp = (const int*)&s4;
        int4 o;
        int* op = (int*)&o;
#pragma unroll
        for (int k = 0; k < 4; k++) {
            int s = sp[k];
            if (s < 0) op[k] = -1;
            else {
                int r = lab[s];                  // root (starts compressed)
                op[k] = baseLocal + (r >> 6) * IMG_W + (r & 63);
            }
        }
        *(int4*)(Li + baseLocal + (i4 >> 6) * IMG_W + (i4 & 63)) = o;
    }
    // ---- edge export: 4 x 64 labels, coalesced -----------------------------
    if (tid < 256) {
        int e = tid >> 6;                        // 0=T,1=B,2=L,3=R
        int q = tid & 63;
        int px = (e == 0) ? q
               : (e == 1) ? (63 * TILE + q)
               : (e == 2) ? (q * TILE)
               :            (q * TILE + 63);
        int s = lab[px];
        int val = -1;
        if (s >= 0) {
            int r = lab[s];
            val = baseLocal + (r >> 6) * IMG_W + (r & 63);
        }
        edges[e * EDGE_N + tile * 64 + q] = val;
    }
    // ---- base BCE: wave shuffle reduce (1 barrier) -------------------------
#pragma unroll
    for (int o = 32; o > 0; o >>= 1) acc += __shfl_down(acc, o);
    if (lane == 0) swf[wave] = acc;
    __syncthreads();                             // also orders rootc/rl
    if (tid == 0) {
        float s = 0.0f;
#pragma unroll
        for (int w = 0; w < 8; w++) s += swf[w];
        partials[blockIdx.x] = s;
        rootCnt[tile] = rootc;
        if (blockIdx.x == 0) *counter = 0u;      // ws is 0xAA-poisoned
    }
}

// ---------------- K2: cross-tile border unites from compact edges -----------
__global__ __launch_bounds__(256) void k_border(const int* __restrict__ edges,
                                                int* __restrict__ L) {
    int gid = blockIdx.x * blockDim.x + threadIdx.x;
    int pair = gid >> 6;                 // wave-uniform
    int lane = gid & 63;
    int a, b, img;
    if (pair < NIMG * 56) {              // vertical: (ty,tx)-(ty,tx+1)
        img = pair / 56;
        int w = pair - img * 56;
        int ty = w / 7, tx = w - ty * 7;
        int tl = img * TPI + ty * 8 + tx;
        a = edges[3 * EDGE_N + tl * 64 + lane];        // right edge of left
        b = edges[2 * EDGE_N + (tl + 1) * 64 + lane];  // left edge of right
    } else {                             // horizontal: (ty,tx)-(ty+1,tx)
        int p2 = pair - NIMG * 56;
        img = p2 / 56;
        int w = p2 - img * 56;
        int ty = w >> 3, tx = w & 7;
        int tu = img * TPI + ty * 8 + tx;
        a = edges[1 * EDGE_N + tu * 64 + lane];        // bottom edge of upper
        b = edges[0 * EDGE_N + (tu + 8) * 64 + lane];  // top edge of lower
    }
    bool c = (a >= 0) && (b >= 0);
    unsigned long long cb = __ballot(c);
    unsigned long long cs = cb & ~(cb << 1);           // contact-run starts
    if ((cs >> lane) & 1ULL)
        uf_unite(L + ((size_t)img << LOGHW), a, b);
}

// ---------------- K3: fused stats (candidate probe) + rv + reduce -----------
// One block (512 thr) per image. Global roots after k_border = {r in
// local-root list : L[r]==r} (unites only demote, never create). Probe ~17K
// dedup'd candidates/image instead of re-reading 33.5MB of L. v = last_root
// if >=1; else lazy minFg scan / 1. rv >= 0 (v<=num, never on this input)
// falls back to in-block full-L selection + correction scan. Last of the 32
// blocks (32-way counter in a 32-block grid — the only safe handshake
// pattern) reduces k_local's 2048 base partials + 32 corrections.
__global__ __launch_bounds__(512) void k_tail(const int* __restrict__ rootCnt,
                                              const int* __restrict__ rootList,
                                              const int* __restrict__ L,
                                              const float* __restrict__ pred,
                                              const float* __restrict__ partials,
                                              float* __restrict__ corr,
                                              unsigned int* __restrict__ counter,
                                              float* __restrict__ out) {
    __shared__ int pre[65];              // inclusive prefix of 64 tile counts
    __shared__ int sc[512], sm[512];
    __shared__ int result;
    __shared__ float sf[512];
    __shared__ double sd[512];
    __shared__ unsigned int oldc;
    int img = blockIdx.x, t = threadIdx.x;
    const int* Li = L + ((size_t)img << LOGHW);

    // ---- tile-count prefix (wave 0, shuffle scan) --------------------------
    if (t < 64) {
        int v = rootCnt[img * TPI + t];
#pragma unroll
        for (int o = 1; o < 64; o <<= 1) {
            int u = __shfl_up(v, o);
            if (t >= o) v += u;
        }
        pre[t + 1] = v;
        if (t == 0) pre[0] = 0;
    }
    if (t == 0) result = -2;
    __syncthreads();
    int C = pre[64];                     // total candidates this image (~17K)

    // ---- candidate probe: count survivors + max survivor, 8-wide batched ---
    int cnt = 0, mx = -1;
    for (int k0 = t; k0 < C; k0 += 4096) {
        int rr0 = -1, rr1 = -1, rr2 = -1, rr3 = -1,
            rr4 = -1, rr5 = -1, rr6 = -1, rr7 = -1;
#define PROBE(J, RR)                                                        \
        {                                                                   \
            int k = k0 + (J) * 512;                                         \
            if (k < C) {                                                    \
                int lo = 0, hi = 64;                                        \
                for (int s = 0; s < 6; s++) {                               \
                    int mid = (lo + hi) >> 1;                               \
                    if (pre[mid] <= k) lo = mid; else hi = mid;             \
                }                                                           \
                RR = rootList[(size_t)(img * TPI + lo) * RTSTRIDE           \
                              + (k - pre[lo])];                             \
            }                                                               \
        }
        PROBE(0, rr0) PROBE(1, rr1) PROBE(2, rr2) PROBE(3, rr3)
        PROBE(4, rr4) PROBE(5, rr5) PROBE(6, rr6) PROBE(7, rr7)
#undef PROBE
#define TEST(RR) if ((RR) >= 0 && Li[RR] == (RR)) { cnt++; mx = max(mx, RR); }
        TEST(rr0) TEST(rr1) TEST(rr2) TEST(rr3)
        TEST(rr4) TEST(rr5) TEST(rr6) TEST(rr7)
#undef TEST
    }
    sc[t] = cnt; sm[t] = mx;
    __syncthreads();
    for (int s = 256; s > 0; s >>= 1) {
        if (t < s) { sc[t] += sc[t + s]; sm[t] = max(sm[t], sm[t + s]); }
        __syncthreads();
    }
    int num = sc[0], last_root = sm[0];
    int v;
    if (last_root >= 1) {                // block-uniform (common case)
        v = last_root;
    } else {
        // rare: lazy minFg = first fg index >= 1 (coalesced Li scan)
        __syncthreads();                 // sc reuse
        int mn = HW;
        for (int i0 = t * 4; i0 < HW; i0 += 2048) {
            int4 l4 = *(const int4*)(Li + i0);
            if (l4.x >= 0 && i0 >= 1) mn = min(mn, i0);
            if (l4.y >= 0) mn = min(mn, i0 + 1);
            if (l4.z >= 0) mn = min(mn, i0 + 2);
            if (l4.w >= 0) mn = min(mn, i0 + 3);
        }
        sc[t] = mn;
        __syncthreads();
        for (int s = 256; s > 0; s >>= 1) {
            if (t < s) sc[t] = min(sc[t], sc[t + s]);
            __syncthreads();
        }
        mn = sc[0];
        v = (last_root == 0) ? ((mn < HW) ? mn : 1) : 1;
        __syncthreads();
    }

    // ---- rare path: select v-th surviving root in raster order -------------
    if (v >= 1 && v <= num) {            // block-uniform branch
        __syncthreads();                 // sc reuse
        int base = t * (HW / 512);       // contiguous 512-px raster range
        int c = 0;
        for (int j = 0; j < 128; j++) {
            int off = base + j * 4;
            int4 l4 = *(const int4*)(Li + off);
            c += (l4.x == off) + (l4.y == off + 1)
               + (l4.z == off + 2) + (l4.w == off + 3);
        }
        sc[t] = c;
        __syncthreads();
        for (int off = 1; off < 512; off <<= 1) {
            int v2 = (t >= off) ? sc[t - off] : 0;
            __syncthreads();
            sc[t] += v2;
            __syncthreads();
        }
        int inc = sc[t], exc = inc - c;
        if (exc < v && v <= inc) {       // my range holds the v-th root
            int need = v - exc, run = 0;
            for (int j = 0; j < 128; j++) {
                int off = base + j * 4;
                int4 l4 = *(const int4*)(Li + off);
                if (l4.x == off)     { run++; if (run == need) result = off; }
                if (l4.y == off + 1) { run++; if (run == need) result = off + 1; }
                if (l4.z == off + 2) { run++; if (run == need) result = off + 2; }
                if (l4.w == off + 3) { run++; if (run == need) result = off + 3; }
                if (run >= need) break;
            }
        }
        __syncthreads();
    }
    int rvv = result;
    float blocksum = 0.0f;
    if (rvv >= 0) {                      // rare path: scan whole image
        const float* pi = pred + ((size_t)img << LOGHW);
        float acc = 0.0f;
        for (int it = 0; it < HW / 2048; it++) {
            int off = it * 2048 + t * 4;
            float4 p4 = *(const float4*)(pi + off);
            int4 l4 = *(const int4*)(Li + off);
            const float* pp = (const float*)&p4;
            const int* lp = (const int*)&l4;
#pragma unroll
            for (int k = 0; k < 4; k++) {
                int p = lp[k];
                if (p < 0) continue;
                int x = p, q = Li[x];
                while (q != x) { x = q; q = Li[x]; }
                if (x == rvv) {
                    float pr = pp[k];
                    acc += fmaxf(__logf(pr), -100.0f)
                         - fmaxf(__logf(1.0f - pr), -100.0f);
                }
            }
        }
        sf[t] = acc;
        __syncthreads();
        for (int s = 256; s > 0; s >>= 1) {
            if (t < s) sf[t] += sf[t + s];
            __syncthreads();
        }
        blocksum = sf[0];
    }
    if (t == 0) {
        __hip_atomic_store(&corr[img], blocksum, __ATOMIC_RELAXED,
                           __HIP_MEMORY_SCOPE_AGENT);
        oldc = __hip_atomic_fetch_add(counter, 1u, __ATOMIC_ACQ_REL,
                                      __HIP_MEMORY_SCOPE_AGENT);
    }
    __syncthreads();
    if (oldc != NIMG - 1) return;
    // ---- last of 32 blocks: final reduce -----------------------------------
    double acc = 0.0;
#pragma unroll
    for (int j = 0; j < 4; j++) acc += (double)partials[t + j * 512];
    if (t < NIMG)
        acc += (double)__hip_atomic_load(&corr[t], __ATOMIC_ACQUIRE,
                                         __HIP_MEMORY_SCOPE_AGENT);
    sd[t] = acc;
    __syncthreads();
    for (int s = 256; s > 0; s >>= 1) {
        if (t < s) sd[t] += sd[t + s];
        __syncthreads();
    }
    if (t == 0) out[0] = (float)(-sd[0] / (double)NTOT);
}

extern "C" void kernel_launch(void* const* d_in, const int* in_sizes, int n_in,
                              void* d_out, int out_size, void* d_ws, size_t ws_size,
                              hipStream_t stream) {
    const float* pred = (const float*)d_in[0];
    float* out = (float*)d_out;

    char* ws = (char*)d_ws;
    int* L = (int*)ws;                                        // 33.5 MB
    int* edges = (int*)(ws + (size_t)NTOT * 4);               // 2 MB (4 dirs)
    int* rootList = edges + 4 * EDGE_N;                       // 16.8 MB
    int* rootCnt = rootList + (size_t)NTILE * RTSTRIDE;       // 8 KB
    float* partials = (float*)(rootCnt + NTILE);              // 8 KB
    float* corr = partials + NTILE;                           // 128 B
    unsigned int* counter = (unsigned int*)(corr + NIMG);     // 4 B

    k_local<<<dim3(NTILE), dim3(512), 0, stream>>>(pred, L, partials, edges,
                                                   rootCnt, rootList, counter);
    k_border<<<dim3(NPAIR * 64 / 256), dim3(256), 0, stream>>>(edges, L);
    k_tail<<<dim3(NIMG), dim3(512), 0, stream>>>(rootCnt, rootList, L, pred,
                                                 partials, corr, counter, out);
}